// Round 1
// baseline (724.828 us; speedup 1.0000x reference)
//
#include <hip/hip_runtime.h>
#include <hip/hip_bf16.h>

// Transducer joint: logits[b,t,u,v] = tanh(enc_proj[b,t,:]+dec_proj[b,u,:]+b1) @ W2 + b2
// B=4 T=256 U=128, ENC=DEC=512, INNER=512, VOCAB=2048
// Main GEMM: M=131072 (one block per (b,t), BM=128 over u), N=2048, K=512, bf16 MFMA.

typedef __attribute__((ext_vector_type(4))) float f32x4;
typedef __attribute__((ext_vector_type(8))) __bf16 bf16x8;
typedef __attribute__((ext_vector_type(8))) unsigned short u16x8;

__device__ __forceinline__ float bf2f(unsigned short u) {
  unsigned int x = ((unsigned int)u) << 16;
  return __builtin_bit_cast(float, x);
}
__device__ __forceinline__ unsigned short f2bf(float f) {
  unsigned int x = __builtin_bit_cast(unsigned int, f);
  x += 0x7fff + ((x >> 16) & 1);   // round-to-nearest-even (values are finite/bounded)
  return (unsigned short)(x >> 16);
}
__device__ __forceinline__ float tanh_fast(float x) {
  // tanh(x) = 1 - 2/(exp(2x)+1); saturates correctly for large |x|
  float e = __expf(2.0f * x);
  return 1.0f - 2.0f * __builtin_amdgcn_rcpf(e + 1.0f);
}

// ---------------- Pass 1: enc_proj (fp32) and dec_proj+b1 (bf16) ----------------
__global__ __launch_bounds__(256) void proj_kernel(
    const float* __restrict__ enc, const float* __restrict__ dec,
    const float* __restrict__ W1, const float* __restrict__ b1,
    float* __restrict__ enc_proj, unsigned short* __restrict__ decb) {
  int gid = blockIdx.x * 256 + threadIdx.x;  // 1536*512 total
  int row = gid >> 9;
  int h = gid & 511;
  if (row < 1024) {                       // enc rows: (b,t)
    const float* x = enc + (size_t)row * 512;
    const float* w = W1 + h;              // W1[k][h], k in [0,512)
    float acc = 0.f;
#pragma unroll 4
    for (int k = 0; k < 512; ++k) acc += x[k] * w[(size_t)k * 512];
    enc_proj[(size_t)row * 512 + h] = acc;
  } else {                                // dec rows: (b,u)
    int r = row - 1024;                   // 0..511
    const float* x = dec + (size_t)r * 512;
    const float* w = W1 + (size_t)512 * 512 + h;  // W1[512+k][h]
    float acc = b1[h];
#pragma unroll 4
    for (int k = 0; k < 512; ++k) acc += x[k] * w[(size_t)k * 512];
    decb[(size_t)r * 512 + h] = f2bf(acc);
  }
}

// ---------------- Pass 2: W2 [512][2048] fp32 -> W2t [2048][512] bf16 ----------------
__global__ __launch_bounds__(256) void w2t_kernel(const float* __restrict__ W2,
                                                  unsigned short* __restrict__ W2t) {
  __shared__ unsigned short tile[32][33];
  int bn = blockIdx.x;   // 64 n-tiles
  int bk = blockIdx.y;   // 16 k-tiles
  int tx = threadIdx.x & 31;
  int ty = threadIdx.x >> 5;  // 0..7
#pragma unroll
  for (int i = 0; i < 32; i += 8)
    tile[ty + i][tx] = f2bf(W2[(size_t)(bk * 32 + ty + i) * 2048 + bn * 32 + tx]);
  __syncthreads();
#pragma unroll
  for (int i = 0; i < 32; i += 8)
    W2t[(size_t)(bn * 32 + ty + i) * 512 + bk * 32 + tx] = tile[tx][ty + i];
}

// ---------------- Pass 3: main fused tanh-GEMM ----------------
// grid (1024, 16): x = (b,t), y = 128-wide n block. 256 threads = 4 waves (2x2 of 64x64).
__global__ __launch_bounds__(256, 2) void trans_kernel(
    const float* __restrict__ enc_proj,        // [1024][512]
    const unsigned short* __restrict__ decb,   // [4][128][512] bf16 (b1 folded in)
    const unsigned short* __restrict__ W2t,    // [2048][512] bf16
    const float* __restrict__ b2,              // [2048]
    float* __restrict__ out) {                 // [1024][128][2048]
  __shared__ unsigned short Al[128][72];  // h tile, rows=u, pad 64->72 (bank spread)
  __shared__ unsigned short Bl[128][72];  // W2^T tile, rows=n

  const int mb = blockIdx.x;       // (b,t)
  const int nb = blockIdx.y;       // n block
  const int b = mb >> 8;
  const int tid = threadIdx.x;
  const int lane = tid & 63;
  const int wid = tid >> 6;
  const int wr = wid >> 1;         // wave row 0..1
  const int wc = wid & 1;          // wave col 0..1

  f32x4 acc[4][4];
#pragma unroll
  for (int i = 0; i < 4; ++i)
#pragma unroll
    for (int j = 0; j < 4; ++j) acc[i][j] = (f32x4){0.f, 0.f, 0.f, 0.f};

  const float* encrow = enc_proj + (size_t)mb * 512;
  const unsigned short* decrow = decb + (size_t)b * 128 * 512;
  const unsigned short* w2base = W2t + (size_t)nb * 128 * 512;

  for (int k0 = 0; k0 < 512; k0 += 64) {
    // ---- stage A (compute tanh) and B (copy) tiles into LDS ----
#pragma unroll
    for (int it = 0; it < 4; ++it) {
      int idx = it * 256 + tid;      // 0..1023
      int row = idx >> 3;            // 0..127
      int kc = (idx & 7) << 3;       // 0,8,..,56
      u16x8 dv = *(const u16x8*)(decrow + (size_t)row * 512 + k0 + kc);
      f32x4 e0 = *(const f32x4*)(encrow + k0 + kc);
      f32x4 e1 = *(const f32x4*)(encrow + k0 + kc + 4);
      u16x8 hv;
#pragma unroll
      for (int j = 0; j < 4; ++j) hv[j] = f2bf(tanh_fast(bf2f(dv[j]) + e0[j]));
#pragma unroll
      for (int j = 0; j < 4; ++j) hv[4 + j] = f2bf(tanh_fast(bf2f(dv[4 + j]) + e1[j]));
      *(u16x8*)&Al[row][kc] = hv;
      *(u16x8*)&Bl[row][kc] = *(const u16x8*)(w2base + (size_t)row * 512 + k0 + kc);
    }
    __syncthreads();

    // ---- fragments + MFMA ----
    const int fr = lane & 15;
    const int fq = lane >> 4;
    bf16x8 af[4][2], bfr[4][2];
#pragma unroll
    for (int mi = 0; mi < 4; ++mi)
#pragma unroll
      for (int kk = 0; kk < 2; ++kk)
        af[mi][kk] = *(const bf16x8*)&Al[wr * 64 + mi * 16 + fr][kk * 32 + fq * 8];
#pragma unroll
    for (int ni = 0; ni < 4; ++ni)
#pragma unroll
      for (int kk = 0; kk < 2; ++kk)
        bfr[ni][kk] = *(const bf16x8*)&Bl[wc * 64 + ni * 16 + fr][kk * 32 + fq * 8];
#pragma unroll
    for (int kk = 0; kk < 2; ++kk)
#pragma unroll
      for (int mi = 0; mi < 4; ++mi)
#pragma unroll
        for (int ni = 0; ni < 4; ++ni)
          acc[mi][ni] = __builtin_amdgcn_mfma_f32_16x16x32_bf16(
              af[mi][kk], bfr[ni][kk], acc[mi][ni], 0, 0, 0);
    __syncthreads();
  }

  // ---- epilogue: +b2, store fp32 ----
  const int ccol = lane & 15;            // C: col = lane&15
  const int crow = (lane >> 4) * 4;      //    row = (lane>>4)*4 + reg
  const size_t outbase = ((size_t)mb << 18) + (size_t)nb * 128;
#pragma unroll
  for (int ni = 0; ni < 4; ++ni) {
    int n = wc * 64 + ni * 16 + ccol;
    float bv = b2[nb * 128 + n];
#pragma unroll
    for (int mi = 0; mi < 4; ++mi) {
#pragma unroll
      for (int r = 0; r < 4; ++r) {
        int u = wr * 64 + mi * 16 + crow + r;
        out[outbase + (size_t)u * 2048 + n] = acc[mi][ni][r] + bv;
      }
    }
  }
}

extern "C" void kernel_launch(void* const* d_in, const int* in_sizes, int n_in,
                              void* d_out, int out_size, void* d_ws, size_t ws_size,
                              hipStream_t stream) {
  const float* enc = (const float*)d_in[0];   // (4,256,512)
  const float* dec = (const float*)d_in[1];   // (4,128,512)
  const float* W1  = (const float*)d_in[2];   // (1024,512)
  const float* b1  = (const float*)d_in[3];   // (512,)
  const float* W2  = (const float*)d_in[4];   // (512,2048)
  const float* b2  = (const float*)d_in[5];   // (2048,)
  float* out = (float*)d_out;                 // (4,256,128,2048)

  char* ws = (char*)d_ws;
  float* enc_proj = (float*)ws;                                   // 2 MB
  unsigned short* decb = (unsigned short*)(ws + (2u << 20));      // 512 KB
  unsigned short* W2t  = (unsigned short*)(ws + (2u << 20) + (512u << 10)); // 2 MB

  proj_kernel<<<3072, 256, 0, stream>>>(enc, dec, W1, b1, enc_proj, decb);
  w2t_kernel<<<dim3(64, 16), 256, 0, stream>>>(W2, W2t);
  trans_kernel<<<dim3(1024, 16), 256, 0, stream>>>(enc_proj, decb, W2t, b2, out);
}

// Round 2
// 696.782 us; speedup vs baseline: 1.0403x; 1.0403x over previous
//
#include <hip/hip_runtime.h>
#include <hip/hip_bf16.h>

// Transducer joint: logits[b,t,u,v] = tanh(enc_proj[b,t,:]+dec_proj[b,u,:]+b1) @ W2 + b2
// B=4 T=256 U=128, ENC=DEC=512, INNER=512, VOCAB=2048
// R2: de-fused. H = tanh(...) materialized bf16 in ws, then m97-structure GEMM
//     (128x128 tile, BK=64, global_load_lds 16B, XCD swizzle, A-panel L2 reuse).

typedef __attribute__((ext_vector_type(4))) float f32x4;
typedef __attribute__((ext_vector_type(8))) __bf16 bf16x8;
typedef __attribute__((ext_vector_type(8))) unsigned short u16x8;
typedef __attribute__((ext_vector_type(4))) unsigned short u16x4;

__device__ __forceinline__ float bf2f(unsigned short u) {
  unsigned int x = ((unsigned int)u) << 16;
  return __builtin_bit_cast(float, x);
}
__device__ __forceinline__ unsigned short f2bf(float f) {
  unsigned int x = __builtin_bit_cast(unsigned int, f);
  x += 0x7fff + ((x >> 16) & 1);   // RNE (values finite/bounded)
  return (unsigned short)(x >> 16);
}
__device__ __forceinline__ float tanh_fast(float x) {
  float e = __expf(2.0f * x);
  return 1.0f - 2.0f * __builtin_amdgcn_rcpf(e + 1.0f);
}

// async global->LDS, 16B per lane; lds dest is wave-uniform base + lane*16
typedef __attribute__((address_space(3))) unsigned int lds_u32;
typedef const __attribute__((address_space(1))) unsigned int glb_u32;
__device__ __forceinline__ void gl16(const void* g, void* l) {
  __builtin_amdgcn_global_load_lds((glb_u32*)g, (lds_u32*)l, 16, 0, 0);
}

// ---------------- Pass 1: enc_proj (fp32) and dec_proj+b1 (bf16) ----------------
// 4 h per thread, f32x4 W1 loads. 1536 rows * 128 threads = 768 blocks.
__global__ __launch_bounds__(256) void proj_kernel(
    const float* __restrict__ enc, const float* __restrict__ dec,
    const float* __restrict__ W1, const float* __restrict__ b1,
    float* __restrict__ enc_proj, unsigned short* __restrict__ decb) {
  int gid = blockIdx.x * 256 + threadIdx.x;
  int row = gid >> 7;
  int h = (gid & 127) << 2;
  if (row < 1024) {                       // enc rows: (b,t)
    const float* x = enc + (size_t)row * 512;
    f32x4 acc = (f32x4){0.f, 0.f, 0.f, 0.f};
#pragma unroll 8
    for (int k = 0; k < 512; ++k) {
      float xv = x[k];
      f32x4 wv = *(const f32x4*)&W1[(size_t)k * 512 + h];
      acc += xv * wv;
    }
    *(f32x4*)&enc_proj[(size_t)row * 512 + h] = acc;
  } else {                                // dec rows: (b,u)
    int r = row - 1024;
    const float* x = dec + (size_t)r * 512;
    f32x4 acc = *(const f32x4*)&b1[h];
#pragma unroll 8
    for (int k = 0; k < 512; ++k) {
      float xv = x[k];
      f32x4 wv = *(const f32x4*)&W1[(size_t)(512 + k) * 512 + h];
      acc += xv * wv;
    }
    u16x4 o;
#pragma unroll
    for (int j = 0; j < 4; ++j) o[j] = f2bf(acc[j]);
    *(u16x4*)&decb[(size_t)r * 512 + h] = o;
  }
}

// ---------------- Pass 2: W2 [512][2048] fp32 -> W2t [2048][512] bf16 ----------------
__global__ __launch_bounds__(256) void w2t_kernel(const float* __restrict__ W2,
                                                  unsigned short* __restrict__ W2t) {
  __shared__ unsigned short tile[32][33];
  int bn = blockIdx.x;
  int bk = blockIdx.y;
  int tx = threadIdx.x & 31;
  int ty = threadIdx.x >> 5;
#pragma unroll
  for (int i = 0; i < 32; i += 8)
    tile[ty + i][tx] = f2bf(W2[(size_t)(bk * 32 + ty + i) * 2048 + bn * 32 + tx]);
  __syncthreads();
#pragma unroll
  for (int i = 0; i < 32; i += 8)
    W2t[(size_t)(bn * 32 + ty + i) * 512 + bk * 32 + tx] = tile[tx][ty + i];
}

// ---------------- Pass 3: H[m][h] = tanh(encp[bt][h] + decb[bu][h]) bf16 ----------------
// m = (b*256+t)*128+u ; 131072 rows, 64 threads/row, 8 elems/thread.
__global__ __launch_bounds__(256) void h_kernel(
    const float* __restrict__ encp, const unsigned short* __restrict__ decb,
    unsigned short* __restrict__ Hout) {
  int gid = blockIdx.x * 256 + threadIdx.x;
  int m = gid >> 6;
  int hc = (gid & 63) << 3;
  int bt = m >> 7;                          // b*256+t
  int bu = ((m >> 15) << 7) | (m & 127);    // b*128+u
  u16x8 dv = *(const u16x8*)(decb + (size_t)bu * 512 + hc);
  f32x4 e0 = *(const f32x4*)(encp + (size_t)bt * 512 + hc);
  f32x4 e1 = *(const f32x4*)(encp + (size_t)bt * 512 + hc + 4);
  u16x8 hv;
#pragma unroll
  for (int j = 0; j < 4; ++j) hv[j] = f2bf(tanh_fast(bf2f(dv[j]) + e0[j]));
#pragma unroll
  for (int j = 0; j < 4; ++j) hv[4 + j] = f2bf(tanh_fast(bf2f(dv[4 + j]) + e1[j]));
  *(u16x8*)(Hout + (size_t)m * 512 + hc) = hv;
}

// ---------------- Pass 4: GEMM out[131072][2048] = H @ W2t^T + b2 ----------------
// m97 structure: 128x128 tile, BK=64, 4 waves (2x2 of 64x64), linear LDS,
// global_load_lds width 16. Grid 16384, XCD-bijective swizzle; 16 consecutive
// logical blocks share one A panel (L2 reuse).
__global__ __launch_bounds__(256) void gemm_kernel(
    const unsigned short* __restrict__ H,     // [131072][512] bf16
    const unsigned short* __restrict__ W2t,   // [2048][512] bf16
    const float* __restrict__ b2,             // [2048]
    float* __restrict__ out) {                // [131072][2048] fp32
  __shared__ unsigned short Al[128 * 64];
  __shared__ unsigned short Bl[128 * 64];

  const int bid = blockIdx.x;
  const int wgid = (bid & 7) * 2048 + (bid >> 3);  // 16384 % 8 == 0 -> bijective
  const int my = wgid >> 4;   // A panel index (0..1023)
  const int ny = wgid & 15;   // N block (0..15)

  const int tid = threadIdx.x;
  const int lane = tid & 63;
  const int w = tid >> 6;
  const int wr = w >> 1;
  const int wc = w & 1;

  f32x4 acc[4][4];
#pragma unroll
  for (int i = 0; i < 4; ++i)
#pragma unroll
    for (int j = 0; j < 4; ++j) acc[i][j] = (f32x4){0.f, 0.f, 0.f, 0.f};

  const unsigned short* hbase = H + (size_t)my * 128 * 512;
  const unsigned short* wbase = W2t + (size_t)ny * 128 * 512;
  const int lrow = lane >> 3;          // 0..7 within chunk-group
  const int lcol = (lane & 7) * 8;     // element col offset

  for (int k0 = 0; k0 < 512; k0 += 64) {
    // stage A and B tiles: 16KB each, 16B/lane, 4 chunk-groups per wave
#pragma unroll
    for (int i = 0; i < 4; ++i) {
      int ch = w * 4 + i;                       // 0..15, covers rows ch*8..ch*8+7
      int row = ch * 8 + lrow;
      gl16(hbase + (size_t)row * 512 + k0 + lcol, &Al[ch * 512]);
      gl16(wbase + (size_t)row * 512 + k0 + lcol, &Bl[ch * 512]);
    }
    __syncthreads();   // compiler emits vmcnt(0) drain + barrier

    const int fr = lane & 15;
    const int fq = lane >> 4;
    bf16x8 af[4][2], bfr[4][2];
#pragma unroll
    for (int mi = 0; mi < 4; ++mi)
#pragma unroll
      for (int kk = 0; kk < 2; ++kk)
        af[mi][kk] = *(const bf16x8*)&Al[(wr * 64 + mi * 16 + fr) * 64 + kk * 32 + fq * 8];
#pragma unroll
    for (int ni = 0; ni < 4; ++ni)
#pragma unroll
      for (int kk = 0; kk < 2; ++kk)
        bfr[ni][kk] = *(const bf16x8*)&Bl[(wc * 64 + ni * 16 + fr) * 64 + kk * 32 + fq * 8];
#pragma unroll
    for (int kk = 0; kk < 2; ++kk)
#pragma unroll
      for (int mi = 0; mi < 4; ++mi)
#pragma unroll
        for (int ni = 0; ni < 4; ++ni)
          acc[mi][ni] = __builtin_amdgcn_mfma_f32_16x16x32_bf16(
              af[mi][kk], bfr[ni][kk], acc[mi][ni], 0, 0, 0);
    __syncthreads();
  }

  // epilogue: +b2, fp32 store
  const int ccol = lane & 15;
  const int crow = (lane >> 4) * 4;
#pragma unroll
  for (int ni = 0; ni < 4; ++ni) {
    int n = ny * 128 + wc * 64 + ni * 16 + ccol;
    float bv = b2[n];
#pragma unroll
    for (int mi = 0; mi < 4; ++mi) {
      size_t mrow = (size_t)my * 128 + wr * 64 + mi * 16 + crow;
#pragma unroll
      for (int r = 0; r < 4; ++r)
        out[(mrow + r) * 2048 + n] = acc[mi][ni][r] + bv;
    }
  }
}

// ---------------- Fallback (R1 fused path) if ws too small ----------------
__global__ __launch_bounds__(256, 2) void trans_kernel(
    const float* __restrict__ enc_proj, const unsigned short* __restrict__ decb,
    const unsigned short* __restrict__ W2t, const float* __restrict__ b2,
    float* __restrict__ out) {
  __shared__ unsigned short Al[128][72];
  __shared__ unsigned short Bl[128][72];
  const int mb = blockIdx.x;
  const int nb = blockIdx.y;
  const int b = mb >> 8;
  const int tid = threadIdx.x;
  const int lane = tid & 63;
  const int wid = tid >> 6;
  const int wr = wid >> 1;
  const int wc = wid & 1;
  f32x4 acc[4][4];
#pragma unroll
  for (int i = 0; i < 4; ++i)
#pragma unroll
    for (int j = 0; j < 4; ++j) acc[i][j] = (f32x4){0.f, 0.f, 0.f, 0.f};
  const float* encrow = enc_proj + (size_t)mb * 512;
  const unsigned short* decrow = decb + (size_t)b * 128 * 512;
  const unsigned short* w2base = W2t + (size_t)nb * 128 * 512;
  for (int k0 = 0; k0 < 512; k0 += 64) {
#pragma unroll
    for (int it = 0; it < 4; ++it) {
      int idx = it * 256 + tid;
      int row = idx >> 3;
      int kc = (idx & 7) << 3;
      u16x8 dv = *(const u16x8*)(decrow + (size_t)row * 512 + k0 + kc);
      f32x4 e0 = *(const f32x4*)(encrow + k0 + kc);
      f32x4 e1 = *(const f32x4*)(encrow + k0 + kc + 4);
      u16x8 hv;
#pragma unroll
      for (int j = 0; j < 4; ++j) hv[j] = f2bf(tanh_fast(bf2f(dv[j]) + e0[j]));
#pragma unroll
      for (int j = 0; j < 4; ++j) hv[4 + j] = f2bf(tanh_fast(bf2f(dv[4 + j]) + e1[j]));
      *(u16x8*)&Al[row][kc] = hv;
      *(u16x8*)&Bl[row][kc] = *(const u16x8*)(w2base + (size_t)row * 512 + k0 + kc);
    }
    __syncthreads();
    const int fr = lane & 15;
    const int fq = lane >> 4;
    bf16x8 af[4][2], bfr[4][2];
#pragma unroll
    for (int mi = 0; mi < 4; ++mi)
#pragma unroll
      for (int kk = 0; kk < 2; ++kk)
        af[mi][kk] = *(const bf16x8*)&Al[wr * 64 + mi * 16 + fr][kk * 32 + fq * 8];
#pragma unroll
    for (int ni = 0; ni < 4; ++ni)
#pragma unroll
      for (int kk = 0; kk < 2; ++kk)
        bfr[ni][kk] = *(const bf16x8*)&Bl[wc * 64 + ni * 16 + fr][kk * 32 + fq * 8];
#pragma unroll
    for (int kk = 0; kk < 2; ++kk)
#pragma unroll
      for (int mi = 0; mi < 4; ++mi)
#pragma unroll
        for (int ni = 0; ni < 4; ++ni)
          acc[mi][ni] = __builtin_amdgcn_mfma_f32_16x16x32_bf16(
              af[mi][kk], bfr[ni][kk], acc[mi][ni], 0, 0, 0);
    __syncthreads();
  }
  const int ccol = lane & 15;
  const int crow = (lane >> 4) * 4;
  const size_t outbase = ((size_t)mb << 18) + (size_t)nb * 128;
#pragma unroll
  for (int ni = 0; ni < 4; ++ni) {
    int n = wc * 64 + ni * 16 + ccol;
    float bv = b2[nb * 128 + n];
#pragma unroll
    for (int mi = 0; mi < 4; ++mi) {
#pragma unroll
      for (int r = 0; r < 4; ++r) {
        int u = wr * 64 + mi * 16 + crow + r;
        out[outbase + (size_t)u * 2048 + n] = acc[mi][ni][r] + bv;
      }
    }
  }
}

extern "C" void kernel_launch(void* const* d_in, const int* in_sizes, int n_in,
                              void* d_out, int out_size, void* d_ws, size_t ws_size,
                              hipStream_t stream) {
  const float* enc = (const float*)d_in[0];
  const float* dec = (const float*)d_in[1];
  const float* W1  = (const float*)d_in[2];
  const float* b1  = (const float*)d_in[3];
  const float* W2  = (const float*)d_in[4];
  const float* b2  = (const float*)d_in[5];
  float* out = (float*)d_out;

  char* ws = (char*)d_ws;
  float* enc_proj = (float*)ws;                                    // 2 MB
  unsigned short* decb = (unsigned short*)(ws + (2u << 20));       // 512 KB
  unsigned short* W2t  = (unsigned short*)(ws + (2u << 20) + (512u << 10)); // 2 MB
  unsigned short* Hbuf = (unsigned short*)(ws + (8u << 20));       // 134.25 MB

  proj_kernel<<<768, 256, 0, stream>>>(enc, dec, W1, b1, enc_proj, decb);
  w2t_kernel<<<dim3(64, 16), 256, 0, stream>>>(W2, W2t);

  if (ws_size >= (160ull << 20)) {
    h_kernel<<<32768, 256, 0, stream>>>(enc_proj, decb, Hbuf);
    gemm_kernel<<<16384, 256, 0, stream>>>(Hbuf, W2t, b2, out);
  } else {
    trans_kernel<<<dim3(1024, 16), 256, 0, stream>>>(enc_proj, decb, W2t, b2, out);
  }
}

// Round 3
// 605.926 us; speedup vs baseline: 1.1962x; 1.1499x over previous
//
#include <hip/hip_runtime.h>
#include <hip/hip_bf16.h>

// Transducer joint: logits[b,t,u,v] = tanh(enc_proj[b,t,:]+dec_proj[b,u,:]+b1) @ W2 + b2
// B=4 T=256 U=128, ENC=DEC=512, INNER=512, VOCAB=2048
// R3: 256x256 8-phase GEMM (T1 XCD swizzle + T2 st_16x32 LDS swizzle + T3/T4
//     counted vmcnt + T5 setprio), de-fused H in ws.

typedef __attribute__((ext_vector_type(4))) float f32x4;
typedef __attribute__((ext_vector_type(8))) __bf16 bf16x8;
typedef __attribute__((ext_vector_type(8))) unsigned short u16x8;
typedef __attribute__((ext_vector_type(4))) unsigned short u16x4;

__device__ __forceinline__ float bf2f(unsigned short u) {
  unsigned int x = ((unsigned int)u) << 16;
  return __builtin_bit_cast(float, x);
}
__device__ __forceinline__ unsigned short f2bf(float f) {
  unsigned int x = __builtin_bit_cast(unsigned int, f);
  x += 0x7fff + ((x >> 16) & 1);   // RNE
  return (unsigned short)(x >> 16);
}
__device__ __forceinline__ float tanh_fast(float x) {
  float e = __expf(2.0f * x);
  return 1.0f - 2.0f * __builtin_amdgcn_rcpf(e + 1.0f);
}

typedef __attribute__((address_space(3))) unsigned int lds_u32;
typedef const __attribute__((address_space(1))) unsigned int glb_u32;
__device__ __forceinline__ void gl16(const void* g, void* l) {
  __builtin_amdgcn_global_load_lds((glb_u32*)g, (lds_u32*)l, 16, 0, 0);
}

#define BAR __builtin_amdgcn_s_barrier()
#define LGKM0 asm volatile("s_waitcnt lgkmcnt(0)" ::: "memory")
#define VMCNT(n) asm volatile("s_waitcnt vmcnt(" #n ")" ::: "memory")
#define MEMPIN asm volatile("" ::: "memory")

// ---------------- Pass 1: enc_proj (fp32) and dec_proj+b1 (bf16) ----------------
__global__ __launch_bounds__(256) void proj_kernel(
    const float* __restrict__ enc, const float* __restrict__ dec,
    const float* __restrict__ W1, const float* __restrict__ b1,
    float* __restrict__ enc_proj, unsigned short* __restrict__ decb) {
  int gid = blockIdx.x * 256 + threadIdx.x;
  int row = gid >> 7;
  int h = (gid & 127) << 2;
  if (row < 1024) {
    const float* x = enc + (size_t)row * 512;
    f32x4 acc = (f32x4){0.f, 0.f, 0.f, 0.f};
#pragma unroll 8
    for (int k = 0; k < 512; ++k) {
      float xv = x[k];
      f32x4 wv = *(const f32x4*)&W1[(size_t)k * 512 + h];
      acc += xv * wv;
    }
    *(f32x4*)&enc_proj[(size_t)row * 512 + h] = acc;
  } else {
    int r = row - 1024;
    const float* x = dec + (size_t)r * 512;
    f32x4 acc = *(const f32x4*)&b1[h];
#pragma unroll 8
    for (int k = 0; k < 512; ++k) {
      float xv = x[k];
      f32x4 wv = *(const f32x4*)&W1[(size_t)(512 + k) * 512 + h];
      acc += xv * wv;
    }
    u16x4 o;
#pragma unroll
    for (int j = 0; j < 4; ++j) o[j] = f2bf(acc[j]);
    *(u16x4*)&decb[(size_t)r * 512 + h] = o;
  }
}

// ---------------- Pass 2: W2 [512][2048] fp32 -> W2t [2048][512] bf16 ----------------
__global__ __launch_bounds__(256) void w2t_kernel(const float* __restrict__ W2,
                                                  unsigned short* __restrict__ W2t) {
  __shared__ unsigned short tile[32][33];
  int bn = blockIdx.x;
  int bk = blockIdx.y;
  int tx = threadIdx.x & 31;
  int ty = threadIdx.x >> 5;
#pragma unroll
  for (int i = 0; i < 32; i += 8)
    tile[ty + i][tx] = f2bf(W2[(size_t)(bk * 32 + ty + i) * 2048 + bn * 32 + tx]);
  __syncthreads();
#pragma unroll
  for (int i = 0; i < 32; i += 8)
    W2t[(size_t)(bn * 32 + ty + i) * 512 + bk * 32 + tx] = tile[tx][ty + i];
}

// ---------------- Pass 3: H[m][h] = tanh(encp[bt][h] + decb[bu][h]) bf16 ----------------
__global__ __launch_bounds__(256) void h_kernel(
    const float* __restrict__ encp, const unsigned short* __restrict__ decb,
    unsigned short* __restrict__ Hout) {
  int gid = blockIdx.x * 256 + threadIdx.x;
  int m = gid >> 6;
  int hc = (gid & 63) << 3;
  int bt = m >> 7;
  int bu = ((m >> 15) << 7) | (m & 127);
  u16x8 dv = *(const u16x8*)(decb + (size_t)bu * 512 + hc);
  f32x4 e0 = *(const f32x4*)(encp + (size_t)bt * 512 + hc);
  f32x4 e1 = *(const f32x4*)(encp + (size_t)bt * 512 + hc + 4);
  u16x8 hv;
#pragma unroll
  for (int j = 0; j < 4; ++j) hv[j] = f2bf(tanh_fast(bf2f(dv[j]) + e0[j]));
#pragma unroll
  for (int j = 0; j < 4; ++j) hv[4 + j] = f2bf(tanh_fast(bf2f(dv[4 + j]) + e1[j]));
  *(u16x8*)(Hout + (size_t)m * 512 + hc) = hv;
}

// ---------------- Pass 4: 256x256 8-phase GEMM ----------------
// Tiles: BM=BN=256, BK=64, nt=8 K-tiles, 4 iterations x 8 phases, 2 tiles/iter.
// LDS 128KB: buf0 {A0,B0}, buf1 {A1,B1}, each tile [256][64] bf16 linear +
// st_16x32 swizzle (byte ^= ((byte>>9)&1)<<5) applied via pre-swizzled gl16 src
// and swizzled ds_read addresses.
// Stage map (iter i, tiles t=2i,t+1): ph1,2: A(t+1)h0,h1->buf1 (i>=1);
// ph3: Bh0(t+2)->buf0; ph4: Bh1,Ah0,Ah1(t+2)->buf0; ph7,8: Bh0,Bh1(t+3)->buf1 (i<=2).
// vmcnt(8) end of ph4, vmcnt(4) end of ph8 (vmcnt(0) at i=3).

__device__ __forceinline__ void stage_half(const char* src, char* dst_region,
                                           int half, int w, int lane) {
#pragma unroll
  for (int r = 0; r < 2; ++r) {
    int dbase = half * 16384 + r * 8192 + w * 1024;
    int d = dbase + lane * 16;
    int s = d ^ (((d >> 9) & 1) << 5);
    gl16(src + (size_t)(s >> 7) * 1024 + (s & 127), dst_region + dbase);
  }
}

__device__ __forceinline__ void load_a(const char* Ar, int a_base, int MH,
                                       bf16x8 (&afr)[4][2]) {
#pragma unroll
  for (int mi = 0; mi < 4; ++mi)
#pragma unroll
    for (int kk = 0; kk < 2; ++kk)
      afr[mi][kk] = *(const bf16x8*)(Ar + a_base + MH * 8192 + mi * 2048 + kk * 64);
}
__device__ __forceinline__ void load_b(const char* Br, int b_base, int NH,
                                       bf16x8 (&bh)[2][2]) {
#pragma unroll
  for (int ni = 0; ni < 2; ++ni)
#pragma unroll
    for (int kk = 0; kk < 2; ++kk)
      bh[ni][kk] = *(const bf16x8*)(Br + b_base + NH * 4096 + ni * 2048 + kk * 64);
}

template <int MH, int NH>
__device__ __forceinline__ void mfma_quad(bf16x8 (&afr)[4][2], bf16x8 (&bh)[2][2],
                                          f32x4 (&acc)[8][4]) {
  __builtin_amdgcn_s_setprio(1);
#pragma unroll
  for (int mi = 0; mi < 4; ++mi)
#pragma unroll
    for (int ni = 0; ni < 2; ++ni)
#pragma unroll
      for (int kk = 0; kk < 2; ++kk)
        acc[MH * 4 + mi][NH * 2 + ni] = __builtin_amdgcn_mfma_f32_16x16x32_bf16(
            afr[mi][kk], bh[ni][kk], acc[MH * 4 + mi][NH * 2 + ni], 0, 0, 0);
  __builtin_amdgcn_s_setprio(0);
}

__global__ __launch_bounds__(512, 2) void gemm8_kernel(
    const unsigned short* __restrict__ H,     // [131072][512] bf16
    const unsigned short* __restrict__ W2t,   // [2048][512] bf16
    const float* __restrict__ b2,             // [2048]
    float* __restrict__ out) {                // [131072][2048] fp32
  __shared__ __align__(1024) char smem[131072];
  char* A0 = smem;
  char* B0 = smem + 32768;
  char* A1 = smem + 65536;
  char* B1 = smem + 98304;

  const int bid = blockIdx.x;
  const int wg = (bid & 7) * 512 + (bid >> 3);   // 4096%8==0 -> bijective
  const int my = wg >> 3;    // 0..511 (A panel; 8 consecutive wg share it)
  const int ny = wg & 7;     // 0..7

  const int tid = threadIdx.x;
  const int lane = tid & 63;
  const int w = tid >> 6;    // 0..7
  const int wm = w >> 2;     // 0..1
  const int wn = w & 3;      // 0..3
  const int fr = lane & 15;
  const int fq = lane >> 4;
  const int xr = (fr & 4) ? 32 : 0;   // swizzle bit: bit9 of row*128 = row bit2 = fr bit2

  const char* ha = (const char*)(H + (size_t)my * 256 * 512);
  const char* wb = (const char*)(W2t + (size_t)ny * 256 * 512);

  const int a_base = (wm * 128 + fr) * 128 + ((fq * 16) ^ xr);
  const int b_base = (wn * 64 + fr) * 128 + ((fq * 16) ^ xr);

  f32x4 acc[8][4];
#pragma unroll
  for (int i = 0; i < 8; ++i)
#pragma unroll
    for (int j = 0; j < 4; ++j) acc[i][j] = (f32x4){0.f, 0.f, 0.f, 0.f};
  bf16x8 afr[4][2];
  bf16x8 bfr[2][2][2];   // [nhalf][ni][kk], both halves live

  // ---- prologue: tile0 -> buf0, tile1 -> buf1, full drain ----
  stage_half(ha, A0, 0, w, lane);        stage_half(ha, A0, 1, w, lane);
  stage_half(wb, B0, 0, w, lane);        stage_half(wb, B0, 1, w, lane);
  stage_half(ha + 128, A1, 0, w, lane);  stage_half(ha + 128, A1, 1, w, lane);
  stage_half(wb + 128, B1, 0, w, lane);  stage_half(wb + 128, B1, 1, w, lane);
  VMCNT(0);
  BAR; MEMPIN;

  for (int i = 0; i < 4; ++i) {
    const int t = 2 * i;
    const char* sA1 = ha + (size_t)(t + 1) * 128;
    const char* sA2 = ha + (size_t)(t + 2) * 128;
    const char* sB2 = wb + (size_t)(t + 2) * 128;
    const char* sB3 = wb + (size_t)(t + 3) * 128;
    const bool si = (i >= 1);
    const bool so = (i <= 2);

    // ---- ph1: quad(0,0) tile t ----
    load_a(A0, a_base, 0, afr);
    load_b(B0, b_base, 0, bfr[0]);
    if (si) stage_half(sA1, A1, 0, w, lane);
    BAR; LGKM0;
    mfma_quad<0, 0>(afr, bfr[0], acc);
    BAR; MEMPIN;

    // ---- ph2: quad(0,1) ----
    load_b(B0, b_base, 1, bfr[1]);
    if (si) stage_half(sA1, A1, 1, w, lane);
    BAR; LGKM0;
    mfma_quad<0, 1>(afr, bfr[1], acc);
    BAR; MEMPIN;

    // ---- ph3: quad(1,0) ----
    load_a(A0, a_base, 1, afr);
    if (so) stage_half(sB2, B0, 0, w, lane);
    BAR; LGKM0;
    mfma_quad<1, 0>(afr, bfr[0], acc);
    BAR; MEMPIN;

    // ---- ph4: quad(1,1); stage rest of tile t+2; vmcnt(8) ----
    if (so) {
      stage_half(sB2, B0, 1, w, lane);
      stage_half(sA2, A0, 0, w, lane);
      stage_half(sA2, A0, 1, w, lane);
    }
    BAR; LGKM0;
    mfma_quad<1, 1>(afr, bfr[1], acc);
    if (i < 3) { VMCNT(8); } else { VMCNT(0); }
    BAR; MEMPIN;

    // ---- ph5: quad(0,0) tile t+1 ----
    load_a(A1, a_base, 0, afr);
    load_b(B1, b_base, 0, bfr[0]);
    BAR; LGKM0;
    mfma_quad<0, 0>(afr, bfr[0], acc);
    BAR; MEMPIN;

    // ---- ph6: quad(0,1) ----
    load_b(B1, b_base, 1, bfr[1]);
    BAR; LGKM0;
    mfma_quad<0, 1>(afr, bfr[1], acc);
    BAR; MEMPIN;

    // ---- ph7: quad(1,0) ----
    load_a(A1, a_base, 1, afr);
    if (so) stage_half(sB3, B1, 0, w, lane);
    BAR; LGKM0;
    mfma_quad<1, 0>(afr, bfr[0], acc);
    BAR; MEMPIN;

    // ---- ph8: quad(1,1); vmcnt(4) ----
    if (so) stage_half(sB3, B1, 1, w, lane);
    BAR; LGKM0;
    mfma_quad<1, 1>(afr, bfr[1], acc);
    if (i < 3) { VMCNT(4); } else { VMCNT(0); }
    BAR; MEMPIN;
  }

  // ---- epilogue: +b2, fp32 store ----
  const int ccol = fr;
  const int crow = fq * 4;
  const size_t orow0 = (size_t)my * 256 + wm * 128;
  const int ncol0 = ny * 256 + wn * 64;
#pragma unroll
  for (int ni4 = 0; ni4 < 4; ++ni4) {
    int n = ncol0 + ni4 * 16 + ccol;
    float bv = b2[n];
#pragma unroll
    for (int mi8 = 0; mi8 < 8; ++mi8) {
      size_t r0 = orow0 + (size_t)mi8 * 16 + crow;
#pragma unroll
      for (int r = 0; r < 4; ++r)
        out[(r0 + r) * 2048 + n] = acc[mi8][ni4][r] + bv;
    }
  }
}

extern "C" void kernel_launch(void* const* d_in, const int* in_sizes, int n_in,
                              void* d_out, int out_size, void* d_ws, size_t ws_size,
                              hipStream_t stream) {
  const float* enc = (const float*)d_in[0];
  const float* dec = (const float*)d_in[1];
  const float* W1  = (const float*)d_in[2];
  const float* b1  = (const float*)d_in[3];
  const float* W2  = (const float*)d_in[4];
  const float* b2  = (const float*)d_in[5];
  float* out = (float*)d_out;

  char* ws = (char*)d_ws;
  float* enc_proj = (float*)ws;                                    // 2 MB
  unsigned short* decb = (unsigned short*)(ws + (2u << 20));       // 512 KB
  unsigned short* W2t  = (unsigned short*)(ws + (2u << 20) + (512u << 10)); // 2 MB
  unsigned short* Hbuf = (unsigned short*)(ws + (8u << 20));       // 134.25 MB

  proj_kernel<<<768, 256, 0, stream>>>(enc, dec, W1, b1, enc_proj, decb);
  w2t_kernel<<<dim3(64, 16), 256, 0, stream>>>(W2, W2t);
  h_kernel<<<32768, 256, 0, stream>>>(enc_proj, decb, Hbuf);
  gemm8_kernel<<<4096, 512, 0, stream>>>(Hbuf, W2t, b2, out);
}